// Round 1
// baseline (339.983 us; speedup 1.0000x reference)
//
#include <hip/hip_runtime.h>

#define DIM    512
#define CH     32
#define KDIM   16384   // CH*DIM
#define BATCH  2048
#define NOUT   512     // projection output dim
#define PWN    (NOUT * KDIM)     // proj_w elements: 8,388,608
#define CONVBLK (PWN / 4 / 256)  // 8192 blocks for the convert half

// ---- 256x256 8-phase GEMM geometry ----
#define BM 256
#define BN 256
#define BK 64
#define KSPLIT 16
#define KC (KDIM / KSPLIT)   // 1024
#define NKT (KC / BK)        // 16 K-tiles per block
#define NITER (NKT / 2)      // 8 main-loop iterations (2 K-tiles each)

typedef short bf16x8 __attribute__((ext_vector_type(8)));
typedef float f32x4  __attribute__((ext_vector_type(4)));

__device__ __forceinline__ float b2f(unsigned short u) {
    union { unsigned int i; float f; } v; v.i = ((unsigned int)u) << 16; return v.f;
}
__device__ __forceinline__ unsigned short f2b(float f) {
    union { float f; unsigned int i; } v; v.f = f;
    unsigned int r = v.i + 0x7fffu + ((v.i >> 16) & 1u);
    return (unsigned short)(r >> 16);
}
// dtype-flag load: isf=1 -> float32 array, isf=0 -> bf16 array
__device__ __forceinline__ float ldv(const void* p, size_t i, int isf) {
    return isf ? ((const float*)p)[i] : b2f(((const unsigned short*)p)[i]);
}
__device__ __forceinline__ int sniff_isf32(const unsigned short* ent_raw) {
    int lane = threadIdx.x & 63;
    unsigned short u = ent_raw[2 * lane];
    int eb = (u >> 8) & 0x7F;
    unsigned long long m = __ballot(eb >= 0x36 && eb < 0x3C);
    return (__popcll(m) < 32) ? 1 : 0;
}

__device__ __forceinline__ void gload_lds16(const unsigned short* g, unsigned short* l) {
    __builtin_amdgcn_global_load_lds(
        (const __attribute__((address_space(1))) void*)g,
        (__attribute__((address_space(3))) void*)l,
        16, 0, 0);
}

// ---------------------------------------------------------------------------
// Fused prep: blocks [0, CONVBLK) convert proj_w -> bf16 pw16;
// blocks [CONVBLK, CONVBLK+BATCH) build feat.
// ---------------------------------------------------------------------------
__global__ __launch_bounds__(256) void prep_kernel(
    const int* __restrict__ h, const int* __restrict__ r,
    const void* __restrict__ ent, const void* __restrict__ rel,
    const void* __restrict__ conv_w, const void* __restrict__ conv_b,
    const void* __restrict__ projw,
    unsigned short* __restrict__ pw16, unsigned short* __restrict__ feat)
{
    const int tid = threadIdx.x;
    const int isf = sniff_isf32((const unsigned short*)ent);

    if (blockIdx.x < CONVBLK) {
        size_t i0 = ((size_t)blockIdx.x * 256 + tid) * 4;
        if (isf) {
            f32x4 v = *(const f32x4*)((const float*)projw + i0);
            unsigned int p0 = (unsigned int)f2b(v[0]) | ((unsigned int)f2b(v[1]) << 16);
            unsigned int p1 = (unsigned int)f2b(v[2]) | ((unsigned int)f2b(v[3]) << 16);
            *(unsigned int*)(pw16 + i0) = p0;
            *(unsigned int*)(pw16 + i0 + 2) = p1;
        } else {
            *(unsigned long long*)(pw16 + i0) =
                *(const unsigned long long*)((const unsigned short*)projw + i0);
        }
        return;
    }

    __shared__ float xs[DIM + 2];
    __shared__ float wS[CH][4];
    const int b = blockIdx.x - CONVBLK;

    const size_t hb = (size_t)h[b] * DIM;
    for (int j = tid; j < DIM; j += 256) xs[1 + j] = ldv(ent, hb + j, isf);
    if (tid == 0) xs[0] = 0.0f;
    if (tid == 1) xs[DIM + 1] = ldv(rel, (size_t)r[b] * DIM, isf);
    if (tid >= 64 && tid < 96) {
        int c = tid - 64;
        wS[c][0] = ldv(conv_w, c * 3 + 0, isf);
        wS[c][1] = ldv(conv_w, c * 3 + 1, isf);
        wS[c][2] = ldv(conv_w, c * 3 + 2, isf);
        wS[c][3] = ldv(conv_b, c, isf);
    }
    __syncthreads();

    unsigned short* fb = feat + (size_t)b * KDIM;
    const int i0 = tid * 2;
    float x0 = xs[i0], x1 = xs[i0 + 1], x2 = xs[i0 + 2], x3 = xs[i0 + 3];
    #pragma unroll 8
    for (int c = 0; c < CH; ++c) {
        float w0 = wS[c][0], w1 = wS[c][1], w2 = wS[c][2], cb = wS[c][3];
        float v0 = fmaxf(fmaf(w0, x0, fmaf(w1, x1, fmaf(w2, x2, cb))), 0.0f);
        float v1 = fmaxf(fmaf(w0, x1, fmaf(w1, x2, fmaf(w2, x3, cb))), 0.0f);
        unsigned int pack = (unsigned int)f2b(v0) | ((unsigned int)f2b(v1) << 16);
        *(unsigned int*)&fb[c * DIM + i0] = pack;
    }
}

// ---------------------------------------------------------------------------
// 8-phase 256x256 bf16 GEMM (m201-style port, plain HIP):
//   Xp[bz][m][n] = sum_{k in bz slice} feat[m,k] * pw16[n,k]
// M=2048 N=512 K=16384; KSPLIT=16 -> grid (8,2,16) = 256 blocks = 1/CU.
// 8 waves (2M x 4N), per-wave 128x64 output, acc[8][4] f32x4.
// LDS 128 KiB: As/Bs [dbuf2][half2][128][64] bf16, staged via
// global_load_lds width-16 (linear dst) + pre-swizzled SOURCE; ds_read uses
// the same involution: phys_slot = logical_slot ^ (row&7) on 16B slots
// (3-bit row XOR -> fragment read spreads over all 32 banks; linear layout
// is a 16-way conflict).
// Schedule invariants (race-freedom):
//   buf0 reads end P3-postbar -> buf0 staged P4/P5 (tile t+2)
//   buf1 reads end P7-postbar -> buf1 staged P8/P1' (tiles t+3 / t+1)
//   vmcnt(4) at P4-end confirms odd tile before P5; at P8-end confirms even
//   tile before next P1; never drained to 0 except final iteration.
// ---------------------------------------------------------------------------
#define BAR()    asm volatile("s_barrier" ::: "memory")
#define WAITL()  asm volatile("s_waitcnt lgkmcnt(0)" ::: "memory")
#define WAITV(n) asm volatile("s_waitcnt vmcnt(" #n ")" ::: "memory")

__global__ __launch_bounds__(512, 2) void gemm_kernel(
    const unsigned short* __restrict__ feat,
    const unsigned short* __restrict__ pw16,
    float* __restrict__ Xp)
{
    __shared__ __align__(16) unsigned short As[2][2][128][64];   // 64 KiB
    __shared__ __align__(16) unsigned short Bs[2][2][128][64];   // 64 KiB

    const int tid  = threadIdx.x;
    const int lane = tid & 63;
    const int w    = tid >> 6;       // 0..7
    const int wm   = w >> 2;         // 0..1 : M half
    const int wn   = w & 3;          // 0..3 : N quarter
    const int fr   = lane & 15;      // fragment row
    const int g    = lane >> 4;      // fragment k-quarter

    const int bx = blockIdx.x, by = blockIdx.y, bz = blockIdx.z;

    const unsigned short* Abase = feat + (size_t)(bx * BM) * KDIM + (size_t)bz * KC;
    const unsigned short* Bbase = pw16 + (size_t)(by * BN) * KDIM + (size_t)bz * KC;

    // staging precompute: idx = q*512+tid; row = q*64 + (tid>>3); slot = tid&7
    const int r0      = tid >> 3;                          // 0..63
    const int kg      = (((tid & 7) ^ (r0 & 7)) << 3);     // pre-swizzled src k (elems)
    const int ldsoff0 = tid << 3;                          // elems (= tid*16 B)

    // read-side swizzled slot offsets (elems), row&7 == fr&7 for all our rows
    const int ps0 = ((0 + g) ^ (fr & 7)) << 3;             // ko=0
    const int ps1 = ((4 + g) ^ (fr & 7)) << 3;             // ko=1
    const int brow = (wn & 1) * 64 + fr;                   // B row base within half

    f32x4 acc[8][4];
    const f32x4 zero = {0.f, 0.f, 0.f, 0.f};
    #pragma unroll
    for (int i = 0; i < 8; ++i)
        #pragma unroll
        for (int j = 0; j < 4; ++j) acc[i][j] = zero;

    bf16x8 af[4][2];    // current mi-half A fragments
    bf16x8 bfr[4][2];   // all four ni B fragments

#define STG(gbase, larr, t, hh) do {                                          \
    const unsigned short* _s = (gbase) + (size_t)((hh) * 128) * KDIM          \
                               + (size_t)((t) * BK) + kg;                     \
    unsigned short* _l = &larr[(t) & 1][hh][0][0];                            \
    gload_lds16(_s + (size_t)r0 * KDIM,        _l + ldsoff0);                 \
    gload_lds16(_s + (size_t)(r0 + 64) * KDIM, _l + ldsoff0 + 4096);          \
} while (0)

#define LDA(d, m0) do {                                                       \
    _Pragma("unroll")                                                         \
    for (int _m = 0; _m < 4; ++_m) {                                          \
        const unsigned short* _rp = &As[d][wm][((m0) + _m) * 16 + fr][0];     \
        af[_m][0] = *(const bf16x8*)(_rp + ps0);                              \
        af[_m][1] = *(const bf16x8*)(_rp + ps1);                              \
    }                                                                         \
} while (0)

#define LDB(d, n0) do {                                                       \
    _Pragma("unroll")                                                         \
    for (int _n = 0; _n < 2; ++_n) {                                          \
        const unsigned short* _rp = &Bs[d][wn >> 1][brow + ((n0) + _n) * 16][0]; \
        bfr[(n0) + _n][0] = *(const bf16x8*)(_rp + ps0);                      \
        bfr[(n0) + _n][1] = *(const bf16x8*)(_rp + ps1);                      \
    }                                                                         \
} while (0)

#define MM(m0, n0) do {                                                       \
    __builtin_amdgcn_s_setprio(1);                                            \
    _Pragma("unroll")                                                         \
    for (int _m = 0; _m < 4; ++_m) {                                          \
        _Pragma("unroll")                                                     \
        for (int _n = 0; _n < 2; ++_n) {                                      \
            acc[(m0)+_m][(n0)+_n] = __builtin_amdgcn_mfma_f32_16x16x32_bf16(  \
                af[_m][0], bfr[(n0)+_n][0], acc[(m0)+_m][(n0)+_n], 0, 0, 0);  \
            acc[(m0)+_m][(n0)+_n] = __builtin_amdgcn_mfma_f32_16x16x32_bf16(  \
                af[_m][1], bfr[(n0)+_n][1], acc[(m0)+_m][(n0)+_n], 0, 0, 0);  \
        }                                                                     \
    }                                                                         \
    __builtin_amdgcn_s_setprio(0);                                            \
} while (0)

    // prologue: fully stage tiles 0 (buf0) and 1 (buf1); confirm tile 0 only
    STG(Abase, As, 0, 0); STG(Abase, As, 0, 1);
    STG(Bbase, Bs, 0, 0); STG(Bbase, Bs, 0, 1);
    STG(Abase, As, 1, 0); STG(Abase, As, 1, 1);
    STG(Bbase, Bs, 1, 0); STG(Bbase, Bs, 1, 1);
    WAITV(8);   // tile0's 8 loads done; tile1's 8 may still fly
    BAR();

    for (int i = 0; i < NITER; ++i) {
        const int t2 = 2 * i;
        const int more = (i + 1 < NITER);
        // ---------- K-tile t2 (buf 0): phases 1-4 ----------
        // P1: reads A(mi0-3)+B(ni0-1) of buf0; stage odd-tile B-halves (buf1)
        LDA(0, 0); LDB(0, 0);
        if (i > 0) { STG(Bbase, Bs, t2 + 1, 0); STG(Bbase, Bs, t2 + 1, 1); }
        BAR(); WAITL();
        MM(0, 0);
        BAR();
        // P2
        LDB(0, 2);
        BAR(); WAITL();
        MM(0, 2);
        BAR();
        // P3 (last buf0 reads retire here)
        LDA(0, 4);
        BAR(); WAITL();
        MM(4, 2);
        BAR();
        // P4: stage next even tile A-halves (buf0 now reusable);
        //     confirm odd tile t2+1 before P5 (allow own 4 loads in flight)
        if (more) { STG(Abase, As, t2 + 2, 0); STG(Abase, As, t2 + 2, 1); }
        BAR(); WAITL();
        MM(4, 0);
        if (more) { WAITV(4); } else { WAITV(0); }
        BAR();
        // ---------- K-tile t2+1 (buf 1): phases 5-8 ----------
        // P5: stage next even tile B-halves (buf0)
        LDA(1, 0); LDB(1, 0);
        if (more) { STG(Bbase, Bs, t2 + 2, 0); STG(Bbase, Bs, t2 + 2, 1); }
        BAR(); WAITL();
        MM(0, 0);
        BAR();
        // P6
        LDB(1, 2);
        BAR(); WAITL();
        MM(0, 2);
        BAR();
        // P7 (last buf1 reads retire here)
        LDA(1, 4);
        BAR(); WAITL();
        MM(4, 2);
        BAR();
        // P8: stage next odd tile A-halves (buf1 reusable);
        //     confirm even tile t2+2 before next P1
        if (more) { STG(Abase, As, t2 + 3, 0); STG(Abase, As, t2 + 3, 1); }
        BAR(); WAITL();
        MM(4, 0);
        if (more) { WAITV(4); } else { WAITV(0); }
        BAR();
    }

#undef STG
#undef LDA
#undef LDB
#undef MM

    // epilogue: C/D layout col=lane&15, row=(lane>>4)*4+reg  [m89-verified]
    float* Xs = Xp + (size_t)bz * BATCH * NOUT;
    const int rbase = bx * BM + wm * 128 + (lane >> 4) * 4;
    const int cbase = by * BN + wn * 64 + (lane & 15);
    #pragma unroll
    for (int mi = 0; mi < 8; ++mi)
        #pragma unroll
        for (int ni = 0; ni < 4; ++ni)
            #pragma unroll
            for (int rr = 0; rr < 4; ++rr) {
                int row = rbase + mi * 16 + rr;
                int col = cbase + ni * 16;
                Xs[(size_t)row * NOUT + col] = acc[mi][ni][rr];
            }
}

// ---------------------------------------------------------------------------
// out[b] = sum_d (sum_bz Xp[bz][b][d] + proj_b[d]) * ent[t[b], d]
// ---------------------------------------------------------------------------
__global__ __launch_bounds__(256) void score_kernel(
    const int* __restrict__ t, const void* __restrict__ ent,
    const float* __restrict__ Xp, const void* __restrict__ projb,
    void* __restrict__ out)
{
    const int lane = threadIdx.x & 63;
    const int wave = threadIdx.x >> 6;
    const int b = blockIdx.x * 4 + wave;
    const int isf = sniff_isf32((const unsigned short*)ent);
    const size_t tb = (size_t)t[b] * DIM;
    float s = 0.f;
    if (isf) {
        const float* te = (const float*)ent + tb;
        const float* pb = (const float*)projb;
        const int d0 = lane * 8;
        #pragma unroll
        for (int jj = 0; jj < 2; ++jj) {
            int d = d0 + jj * 4;
            f32x4 xp = *(const f32x4*)(pb + d);
            #pragma unroll
            for (int z = 0; z < KSPLIT; ++z)
                xp += *(const f32x4*)(Xp + (size_t)z * BATCH * NOUT + (size_t)b * NOUT + d);
            f32x4 tv = *(const f32x4*)(te + d);
            s += xp[0]*tv[0] + xp[1]*tv[1] + xp[2]*tv[2] + xp[3]*tv[3];
        }
    } else {
        #pragma unroll
        for (int j = 0; j < 8; ++j) {
            int d = lane + 64 * j;
            float xp = ldv(projb, d, 0);
            #pragma unroll
            for (int z = 0; z < KSPLIT; ++z)
                xp += Xp[(size_t)z * BATCH * NOUT + (size_t)b * NOUT + d];
            s += xp * ldv(ent, tb + d, 0);
        }
    }
    #pragma unroll
    for (int o = 32; o; o >>= 1) s += __shfl_xor(s, o, 64);
    if (lane == 0) {
        if (isf) ((float*)out)[b] = s;
        else     ((unsigned short*)out)[b] = f2b(s);
    }
}

// ---------------------------------------------------------------------------
extern "C" void kernel_launch(void* const* d_in, const int* in_sizes, int n_in,
                              void* d_out, int out_size, void* d_ws, size_t ws_size,
                              hipStream_t stream)
{
    const int* h = (const int*)d_in[0];
    const int* r = (const int*)d_in[1];
    const int* t = (const int*)d_in[2];
    const void* ent    = d_in[3];
    const void* rel    = d_in[4];
    const void* conv_w = d_in[5];
    const void* conv_b = d_in[6];
    const void* projw  = d_in[7];
    const void* projb  = d_in[8];

    unsigned short* feat = (unsigned short*)d_ws;                         // 64 MiB
    unsigned short* pw16 = (unsigned short*)((char*)d_ws + (size_t)BATCH * KDIM * 2);
    float* Xp = (float*)((char*)pw16 + (size_t)PWN * 2);                  // KSPLIT x 4 MiB

    prep_kernel<<<CONVBLK + BATCH, 256, 0, stream>>>(h, r, ent, rel, conv_w, conv_b,
                                                     projw, pw16, feat);
    gemm_kernel<<<dim3(BATCH / BM, NOUT / BN, KSPLIT), 512, 0, stream>>>(feat, pw16, Xp);
    score_kernel<<<BATCH / 4, 256, 0, stream>>>(t, ent, Xp, projb, d_out);
}